// Round 6
// baseline (62.486 us; speedup 1.0000x reference)
//
#include <hip/hip_runtime.h>
#include <math.h>

// Poincare-ball KG scoring (MuRP-style) for MI355X, v6.
// Diagnosis R2-R5: time invariant (~50us) to gather bytes, mechanism, occupancy.
// Remaining constants attacked here:
//   (1) per-wave exposed gather latency -> grid-stride software pipeline,
//       LDS double-buffer, counted s_waitcnt vmcnt(7) (never 0 in steady state)
//   (2) 16x 64B half-line transactions per gather inst -> 8 lanes/element
//       => each global_load_lds moves 8 full 128B-contiguous lines.

#define EPSF 1e-5f
#define MAXN (1.0f - 1e-5f)

__device__ __forceinline__ float dot4(const float4 a, const float4 b) {
    return a.x*b.x + a.y*b.y + a.z*b.z + a.w*b.w;
}

// pack two f32 (bit patterns lo,hi) into one u32 of two bf16, RTNE
__device__ __forceinline__ unsigned bfpack(unsigned lo, unsigned hi) {
    unsigned bl = (lo + 0x7FFFu + ((lo >> 16) & 1u)) >> 16;
    unsigned bh = (hi + 0x7FFFu + ((hi >> 16) & 1u)) & 0xFFFF0000u;
    return (bl & 0xFFFFu) | bh;
}

__global__ __launch_bounds__(256) void cvt_bf16_kernel(
    const uint4* __restrict__ src, uint4* __restrict__ dst, int ngroups)
{
    int i = blockIdx.x * 256 + threadIdx.x;
    if (i >= ngroups) return;
    uint4 a = src[2*i], b = src[2*i+1];
    uint4 o;
    o.x = bfpack(a.x, a.y); o.y = bfpack(a.z, a.w);
    o.z = bfpack(b.x, b.y); o.w = bfpack(b.z, b.w);
    dst[i] = o;
}

__device__ __forceinline__ float bflo(unsigned u){ return __uint_as_float(u<<16); }
__device__ __forceinline__ float bfhi(unsigned u){ return __uint_as_float(u&0xFFFF0000u); }

__device__ __forceinline__ void gload_lds16(const void* g, void* l) {
    typedef const __attribute__((address_space(1))) unsigned int GU;
    typedef __attribute__((address_space(3))) unsigned int LU;
    __builtin_amdgcn_global_load_lds((GU*)g, (LU*)l, 16, 0, 0);
}

// 8 lanes/element, 8 elements per batch per wave, grid-stride over batches,
// 2-deep pipelined LDS double-buffer (4KiB/buffer/wave, 32KiB/block).
__global__ __launch_bounds__(256, 4) void poincare_score_pipe_kernel(
    const char* __restrict__ Ehb, const float* __restrict__ rvh,
    const float* __restrict__ W, const float* __restrict__ bias0,
    const float* __restrict__ bias1, const int* __restrict__ head_idx,
    const int* __restrict__ rel_idx, const int* __restrict__ tail_idx,
    float* __restrict__ out, int total, int nb, int stride)
{
    __shared__ uint4 lds[4][2][256];       // 32 KiB/block

    const int lane = threadIdx.x & 63;
    const int wave = threadIdx.x >> 6;
    const int sub  = lane & 7;             // lane within element (8)
    const int eg   = lane >> 3;            // element within batch (8)
    const int wid  = blockIdx.x * 4 + wave;
    if (wid >= nb) return;                 // wave-uniform

    const int tmax = total - 1;

    // ---- prolog: idx(b0) -> gathers(b0) -> idx(b1) ----
    int b = wid;
    int e0 = b*8 + eg; e0 = e0 > tmax ? tmax : e0;
    int hi0 = head_idx[e0], ri0 = rel_idx[e0], ti0 = tail_idx[e0];
    {
        const char* hg = Ehb + ((size_t)(unsigned)hi0 << 8) + (sub << 4);
        const char* tg = Ehb + ((size_t)(unsigned)ti0 << 8) + (sub << 4);
        uint4* bp = &lds[wave][0][0];
        gload_lds16(hg,       bp);         gload_lds16(hg + 128, bp + 64);
        gload_lds16(tg,       bp + 128);   gload_lds16(tg + 128, bp + 192);
    }
    int b1 = b + stride; b1 = b1 >= nb ? nb - 1 : b1;
    int e1 = b1*8 + eg; e1 = e1 > tmax ? tmax : e1;
    int hi1 = head_idx[e1], ri1 = rel_idx[e1], ti1 = tail_idx[e1];

    int pb = 0;
    for (; b < nb; b += stride) {
        const bool has_next = (b + stride) < nb;
        // issue next batch's gathers into the other buffer (4 async insts)
        if (has_next) {
            const char* hg = Ehb + ((size_t)(unsigned)hi1 << 8) + (sub << 4);
            const char* tg = Ehb + ((size_t)(unsigned)ti1 << 8) + (sub << 4);
            uint4* bp = &lds[wave][pb ^ 1][0];
            gload_lds16(hg,       bp);         gload_lds16(hg + 128, bp + 64);
            gload_lds16(tg,       bp + 128);   gload_lds16(tg + 128, bp + 192);
        }
        // prefetch idx two batches ahead (3 loads, stay in flight)
        int b2 = b + 2*stride; b2 = b2 >= nb ? nb - 1 : b2;
        int e2 = b2*8 + eg; e2 = e2 > tmax ? tmax : e2;
        int hi2 = head_idx[e2], ri2 = rel_idx[e2], ti2 = tail_idx[e2];

        // counted wait: keep the 7 newest (4 gathers(next) + 3 idx) in flight,
        // drain gathers(current) + everything older. Last iter: drain all.
        if (has_next) asm volatile("s_waitcnt vmcnt(7)" ::: "memory");
        else          asm volatile("s_waitcnt vmcnt(0)" ::: "memory");
        __builtin_amdgcn_sched_barrier(0);

        const uint4* __restrict__ cur = &lds[wave][pb][0];
        const float4* __restrict__ rrow = (const float4*)rvh + (size_t)ri0*32 + sub*2;
        const float4* __restrict__ wrow = (const float4*)W   + (size_t)ri0*32 + sub*2;

        float H2=0.f,T2=0.f,R2=0.f,TR=0.f,HW2=0.f,HWT=0.f,HWR=0.f;
#pragma unroll
        for (int c = 0; c < 2; ++c) {
            uint4 hq = cur[c*64 + lane];             // dims sub*8 + c*64 .. +8
            uint4 tq = cur[128 + c*64 + lane];
            float4 r0 = rrow[c*16], r1 = rrow[c*16 + 1];
            float4 w0 = wrow[c*16], w1 = wrow[c*16 + 1];

            float4 ha = make_float4(bflo(hq.x),bfhi(hq.x),bflo(hq.y),bfhi(hq.y));
            float4 hb = make_float4(bflo(hq.z),bfhi(hq.z),bflo(hq.w),bfhi(hq.w));
            float4 ta = make_float4(bflo(tq.x),bfhi(tq.x),bflo(tq.y),bfhi(tq.y));
            float4 tb = make_float4(bflo(tq.z),bfhi(tq.z),bflo(tq.w),bfhi(tq.w));

            float4 hwa, hwb;
            hwa.x=ha.x*w0.x; hwa.y=ha.y*w0.y; hwa.z=ha.z*w0.z; hwa.w=ha.w*w0.w;
            hwb.x=hb.x*w1.x; hwb.y=hb.y*w1.y; hwb.z=hb.z*w1.z; hwb.w=hb.w*w1.w;

            H2  += dot4(ha,ha)   + dot4(hb,hb);
            T2  += dot4(ta,ta)   + dot4(tb,tb);
            R2  += dot4(r0,r0)   + dot4(r1,r1);
            TR  += dot4(ta,r0)   + dot4(tb,r1);
            HW2 += dot4(hwa,hwa) + dot4(hwb,hwb);
            HWT += dot4(hwa,ta)  + dot4(hwb,tb);
            HWR += dot4(hwa,r0)  + dot4(hwb,r1);
        }
        // reduce across the 8 lanes of each element (3 steps, batched)
#pragma unroll
        for (int m = 1; m <= 4; m <<= 1) {
            H2  += __shfl_xor(H2,  m);
            T2  += __shfl_xor(T2,  m);
            R2  += __shfl_xor(R2,  m);
            TR  += __shfl_xor(TR,  m);
            HW2 += __shfl_xor(HW2, m);
            HWT += __shfl_xor(HWT, m);
            HWR += __shfl_xor(HWR, m);
        }

        // ---- scalar finish ----
        float nh = sqrtf(H2 + 1e-15f);
        float sh = (nh > MAXN) ? (MAXN / nh) : 1.0f;
        float h2 = H2 * sh * sh;

        float nt = sqrtf(T2 + 1e-15f);
        float st = (nt > MAXN) ? (MAXN / nt) : 1.0f;
        float t2 = T2 * st * st;

        float nr = sqrtf(R2 + 1e-15f);
        float sr = (nr > MAXN) ? (MAXN / nr) : 1.0f;
        float r2 = R2 * sr * sr;

        float xy = TR * st * sr;

        float nl = sqrtf(h2 + 1e-15f);
        nl = fminf(fmaxf(nl, EPSF), MAXN);
        float lf = 0.5f * logf((1.0f + nl) / (1.0f - nl)) / nl;  // artanh/n
        float a0 = lf * sh;
        float v2 = a0 * a0 * HW2;

        float nv = fmaxf(sqrtf(v2 + 1e-15f), EPSF);
        float ef = tanhf(nv) / nv;
        float b0 = ef * a0;
        float hd2 = b0 * b0 * HW2;

        float nhd = sqrtf(hd2 + 1e-15f);
        float shd = (nhd > MAXN) ? (MAXN / nhd) : 1.0f;
        float bb = b0 * shd;
        hd2 = bb * bb * HW2;

        float ct  = 1.0f + 2.0f * xy + r2;
        float cr  = 1.0f - t2;
        float den = fmaxf(1.0f + 2.0f * xy + t2 * r2, EPSF);
        float id  = 1.0f / den;
        float p = id * ct * st;
        float q = id * cr * sr;
        float tl2 = p*p*T2 + 2.0f*p*q*TR + q*q*R2;

        float ntl = sqrtf(tl2 + 1e-15f);
        float stl = (ntl > MAXN) ? (MAXN / ntl) : 1.0f;
        p *= stl; q *= stl;
        tl2 = tl2 * stl * stl;

        float hdtl = bb * (p * HWT + q * HWR);
        float d2   = hd2 + tl2 - 2.0f * hdtl;
        float dn   = fmaxf((1.0f - hd2) * (1.0f - tl2), EPSF);
        float arg  = fmaxf(1.0f + 2.0f * d2 / dn, 1.0f + 1e-7f);
        float dist = acoshf(arg);

        int e = b*8 + eg;
        if (sub == 0 && e < total)
            out[e] = bias0[hi0] + bias1[ti0] - dist;

        // rotate pipeline registers
        hi0 = hi1; ri0 = ri1; ti0 = ti1;
        hi1 = hi2; ri1 = ri2; ti1 = ti2;
        pb ^= 1;
    }
}

// f32 fallback (v3 path) if ws too small for the bf16 copy of Eh
__global__ __launch_bounds__(256) void poincare_score_f32_kernel(
    const float* __restrict__ Eh, const float* __restrict__ rvh,
    const float* __restrict__ W, const float* __restrict__ bias0,
    const float* __restrict__ bias1, const int* __restrict__ head_idx,
    const int* __restrict__ rel_idx, const int* __restrict__ tail_idx,
    float* __restrict__ out, int total)
{
    const int tid   = threadIdx.x;
    const int lane4 = tid & 3;
    const int e     = blockIdx.x * 64 + (tid >> 2);
    if (e >= total) return;

    const int hi = head_idx[e];
    const int ri = rel_idx[e];
    const int ti = tail_idx[e];

    const float4* __restrict__ Eh4  = reinterpret_cast<const float4*>(Eh);
    const float4* __restrict__ rvh4 = reinterpret_cast<const float4*>(rvh);
    const float4* __restrict__ W4   = reinterpret_cast<const float4*>(W);

    const float4* __restrict__ hrow = Eh4  + (size_t)hi * 32 + lane4;
    const float4* __restrict__ trow = Eh4  + (size_t)ti * 32 + lane4;
    const float4* __restrict__ rrow = rvh4 + (size_t)ri * 32 + lane4;
    const float4* __restrict__ wrow = W4   + (size_t)ri * 32 + lane4;

    float H2 = 0.f, T2 = 0.f, R2 = 0.f, TR = 0.f;
    float HW2 = 0.f, HWT = 0.f, HWR = 0.f;
#pragma unroll
    for (int j = 0; j < 8; ++j) {
        float4 h = hrow[j * 4];
        float4 t = trow[j * 4];
        float4 r = rrow[j * 4];
        float4 w = wrow[j * 4];
        float4 hw;
        hw.x = h.x * w.x; hw.y = h.y * w.y; hw.z = h.z * w.z; hw.w = h.w * w.w;
        H2  += dot4(h, h);
        T2  += dot4(t, t);
        R2  += dot4(r, r);
        TR  += dot4(t, r);
        HW2 += dot4(hw, hw);
        HWT += dot4(hw, t);
        HWR += dot4(hw, r);
    }
#pragma unroll
    for (int m = 1; m <= 2; m <<= 1) {
        H2  += __shfl_xor(H2,  m);
        T2  += __shfl_xor(T2,  m);
        R2  += __shfl_xor(R2,  m);
        TR  += __shfl_xor(TR,  m);
        HW2 += __shfl_xor(HW2, m);
        HWT += __shfl_xor(HWT, m);
        HWR += __shfl_xor(HWR, m);
    }

    float nh = sqrtf(H2 + 1e-15f);
    float sh = (nh > MAXN) ? (MAXN / nh) : 1.0f;
    float h2 = H2 * sh * sh;
    float nt = sqrtf(T2 + 1e-15f);
    float st = (nt > MAXN) ? (MAXN / nt) : 1.0f;
    float t2 = T2 * st * st;
    float nr = sqrtf(R2 + 1e-15f);
    float sr = (nr > MAXN) ? (MAXN / nr) : 1.0f;
    float r2 = R2 * sr * sr;
    float xy = TR * st * sr;

    float nl = sqrtf(h2 + 1e-15f);
    nl = fminf(fmaxf(nl, EPSF), MAXN);
    float lf = 0.5f * logf((1.0f + nl) / (1.0f - nl)) / nl;
    float a0 = lf * sh;
    float v2 = a0 * a0 * HW2;
    float nv = fmaxf(sqrtf(v2 + 1e-15f), EPSF);
    float ef = tanhf(nv) / nv;
    float b0 = ef * a0;
    float hd2 = b0 * b0 * HW2;
    float nhd = sqrtf(hd2 + 1e-15f);
    float shd = (nhd > MAXN) ? (MAXN / nhd) : 1.0f;
    float b = b0 * shd;
    hd2 = b * b * HW2;

    float ct  = 1.0f + 2.0f * xy + r2;
    float cr  = 1.0f - t2;
    float den = fmaxf(1.0f + 2.0f * xy + t2 * r2, EPSF);
    float id  = 1.0f / den;
    float p = id * ct * st;
    float q = id * cr * sr;
    float tl2 = p * p * T2 + 2.0f * p * q * TR + q * q * R2;
    float ntl = sqrtf(tl2 + 1e-15f);
    float stl = (ntl > MAXN) ? (MAXN / ntl) : 1.0f;
    p *= stl; q *= stl;
    tl2 = tl2 * stl * stl;

    float hdtl = b * (p * HWT + q * HWR);
    float d2   = hd2 + tl2 - 2.0f * hdtl;
    float dn   = fmaxf((1.0f - hd2) * (1.0f - tl2), EPSF);
    float arg  = fmaxf(1.0f + 2.0f * d2 / dn, 1.0f + 1e-7f);
    float dist = acoshf(arg);

    if (lane4 == 0) {
        out[e] = bias0[hi] + bias1[ti] - dist;
    }
}

extern "C" void kernel_launch(void* const* d_in, const int* in_sizes, int n_in,
                              void* d_out, int out_size, void* d_ws, size_t ws_size,
                              hipStream_t stream) {
    const float* Eh       = (const float*)d_in[0];
    const float* rvh      = (const float*)d_in[1];
    const float* W        = (const float*)d_in[2];
    const float* bias0    = (const float*)d_in[3];
    const float* bias1    = (const float*)d_in[4];
    const int*   head_idx = (const int*)d_in[5];
    const int*   rel_idx  = (const int*)d_in[6];
    const int*   tail_idx = (const int*)d_in[7];
    float* out = (float*)d_out;

    const int total = in_sizes[5];             // B*K = 262144
    const int n_eh  = in_sizes[0];             // N_ENT * DIM
    const size_t need = (size_t)n_eh * 2;      // bf16 bytes

    if (ws_size >= need && (n_eh & 7) == 0) {
        const int ngroups = n_eh / 8;
        const int cblocks = (ngroups + 255) / 256;
        cvt_bf16_kernel<<<cblocks, 256, 0, stream>>>(
            (const uint4*)Eh, (uint4*)d_ws, ngroups);

        const int nb      = (total + 7) / 8;   // batches of 8 elements
        const int pblocks = 1280;              // 5 blocks/CU target
        const int stride  = pblocks * 4;       // total waves
        poincare_score_pipe_kernel<<<pblocks, 256, 0, stream>>>(
            (const char*)d_ws, rvh, W, bias0, bias1,
            head_idx, rel_idx, tail_idx, out, total, nb, stride);
    } else {
        const int blocks = (total + 63) / 64;
        poincare_score_f32_kernel<<<blocks, 256, 0, stream>>>(
            Eh, rvh, W, bias0, bias1, head_idx, rel_idx, tail_idx, out, total);
    }
}

// Round 7
// 53.889 us; speedup vs baseline: 1.1595x; 1.1595x over previous
//
#include <hip/hip_runtime.h>
#include <math.h>

// Poincare-ball KG scoring (MuRP-style) for MI355X, v7.
// Theory: TA/L1 segment-rate bound (~4cy/segment). Cuts:
//  - h/t gathers: 4 full 256B rows per global_load_lds inst (16 lanes/row,
//    pre-swizzled global source, linear LDS dest) -> 32 segs/wave (was 128)
//  - rvh|W packed per-relation bf16 row (512B) in ws -> 8 insts/wave (was 16)
// Compute structure identical to v5 (best so far).

#define EPSF 1e-5f
#define MAXN (1.0f - 1e-5f)

__device__ __forceinline__ float dot4(const float4 a, const float4 b) {
    return a.x*b.x + a.y*b.y + a.z*b.z + a.w*b.w;
}

__device__ __forceinline__ unsigned bfpack(unsigned lo, unsigned hi) {
    unsigned bl = (lo + 0x7FFFu + ((lo >> 16) & 1u)) >> 16;
    unsigned bh = (hi + 0x7FFFu + ((hi >> 16) & 1u)) & 0xFFFF0000u;
    return (bl & 0xFFFFu) | bh;
}

__device__ __forceinline__ float bflo(unsigned u){ return __uint_as_float(u<<16); }
__device__ __forceinline__ float bfhi(unsigned u){ return __uint_as_float(u&0xFFFF0000u); }

__device__ __forceinline__ void gload_lds16(const void* g, void* l) {
    typedef const __attribute__((address_space(1))) unsigned int GU;
    typedef __attribute__((address_space(3))) unsigned int LU;
    __builtin_amdgcn_global_load_lds((GU*)g, (LU*)l, 16, 0, 0);
}

// Eh f32 -> bf16 (ngE groups of 8), then rvh|W -> packed bf16 rows
// dstRW layout per relation: 16 uint4 of r (128 bf16), 16 uint4 of w.
__global__ __launch_bounds__(256) void cvt_kernel(
    const uint4* __restrict__ Eh, const uint4* __restrict__ rvh,
    const uint4* __restrict__ W, uint4* __restrict__ dstE,
    uint4* __restrict__ dstRW, int ngE, int nRel)
{
    int i = blockIdx.x * 256 + threadIdx.x;
    if (i < ngE) {
        uint4 a = Eh[2*i], b = Eh[2*i+1];
        uint4 o;
        o.x = bfpack(a.x, a.y); o.y = bfpack(a.z, a.w);
        o.z = bfpack(b.x, b.y); o.w = bfpack(b.z, b.w);
        dstE[i] = o;
    } else {
        int j = i - ngE;                       // [0, nRel*32)
        if (j < nRel * 32) {
            int rel = j >> 5, q = j & 31;      // q<16: r chunk q; q>=16: w chunk q-16
            const uint4* src = (q < 16) ? (rvh + (size_t)rel*32 + q*2)
                                        : (W   + (size_t)rel*32 + (q-16)*2);
            uint4 a = src[0], b = src[1];
            uint4 o;
            o.x = bfpack(a.x, a.y); o.y = bfpack(a.z, a.w);
            o.z = bfpack(b.x, b.y); o.w = bfpack(b.z, b.w);
            dstRW[(size_t)rel*32 + q] = o;
        }
    }
}

// 4 lanes per element, 16 elements per wave, 4 waves per block.
// LDS per wave: h in uint4 [0..256), t in [256..512).
// Gather inst g covers elements ebase+4g..+3: lane l fetches row of element
// ebase+4g+(l&3), chunk l>>2 (16B). Placement: (chunk c, row jm) at g*64+c*4+jm.
__global__ __launch_bounds__(256, 4) void poincare_score_v7_kernel(
    const char* __restrict__ Ehb, const uint4* __restrict__ RW,
    const float* __restrict__ bias0, const float* __restrict__ bias1,
    const int* __restrict__ head_idx, const int* __restrict__ rel_idx,
    const int* __restrict__ tail_idx, float* __restrict__ out, int total)
{
    __shared__ uint4 lds[4][512];              // 32 KiB/block

    const int lane  = threadIdx.x & 63;
    const int wave  = threadIdx.x >> 6;
    const int sub   = lane & 3;
    const int j     = lane >> 2;               // own element within wave batch
    const int ebase = blockIdx.x * 64 + wave * 16;
    const int tmax  = total - 1;

    // own element's indices (for compute + output)
    const int e  = (ebase + j > tmax) ? tmax : (ebase + j);
    const int hi = head_idx[e];
    const int ri = rel_idx[e];
    const int ti = tail_idx[e];

    // bias early (sub==0 lanes only; used at the very end)
    float bsum = 0.0f;
    if (sub == 0) bsum = bias0[hi] + bias1[ti];

    // gather-role indices: inst g needs element ebase + 4g + (lane&3)
    int hgi[4], tgi[4];
#pragma unroll
    for (int g = 0; g < 4; ++g) {
        int ee = ebase + 4*g + (lane & 3);
        ee = (ee > tmax) ? tmax : ee;
        hgi[g] = head_idx[ee];
        tgi[g] = tail_idx[ee];
    }

    uint4* __restrict__ ldsw = lds[wave];
    const int chunk = lane >> 2;               // 0..15, 16B units within row

    // 8 async gather insts; each = 4 contiguous 256B row segments
#pragma unroll
    for (int g = 0; g < 4; ++g)
        gload_lds16(Ehb + ((size_t)(unsigned)hgi[g] << 8) + (chunk << 4),
                    (void*)(ldsw + g * 64));
#pragma unroll
    for (int g = 0; g < 4; ++g)
        gload_lds16(Ehb + ((size_t)(unsigned)tgi[g] << 8) + (chunk << 4),
                    (void*)(ldsw + 256 + g * 64));

    const uint4* __restrict__ rwrow = RW + (size_t)ri * 32;  // r[0..16) w[16..32)

    // one wait for the gather burst (per-wave; LDS written by own wave only)
    asm volatile("s_waitcnt vmcnt(0)" ::: "memory");
    __builtin_amdgcn_sched_barrier(0);

    float H2=0.f,T2=0.f,R2=0.f,TR=0.f,HW2=0.f,HWT=0.f,HWR=0.f;
    const int rbase = (j >> 2) * 64 + (j & 3);
#pragma unroll
    for (int k = 0; k < 4; ++k) {
        const int c = sub + 4*k;               // chunk = dims [c*8, c*8+8)
        uint4 hq = ldsw[rbase + c*4];
        uint4 tq = ldsw[256 + rbase + c*4];
        uint4 rq = rwrow[c];
        uint4 wq = rwrow[16 + c];

        float4 ha = make_float4(bflo(hq.x),bfhi(hq.x),bflo(hq.y),bfhi(hq.y));
        float4 hb = make_float4(bflo(hq.z),bfhi(hq.z),bflo(hq.w),bfhi(hq.w));
        float4 ta = make_float4(bflo(tq.x),bfhi(tq.x),bflo(tq.y),bfhi(tq.y));
        float4 tb = make_float4(bflo(tq.z),bfhi(tq.z),bflo(tq.w),bfhi(tq.w));
        float4 ra = make_float4(bflo(rq.x),bfhi(rq.x),bflo(rq.y),bfhi(rq.y));
        float4 rb = make_float4(bflo(rq.z),bfhi(rq.z),bflo(rq.w),bfhi(rq.w));
        float4 wa = make_float4(bflo(wq.x),bfhi(wq.x),bflo(wq.y),bfhi(wq.y));
        float4 wb = make_float4(bflo(wq.z),bfhi(wq.z),bflo(wq.w),bfhi(wq.w));

        float4 hwa, hwb;
        hwa.x=ha.x*wa.x; hwa.y=ha.y*wa.y; hwa.z=ha.z*wa.z; hwa.w=ha.w*wa.w;
        hwb.x=hb.x*wb.x; hwb.y=hb.y*wb.y; hwb.z=hb.z*wb.z; hwb.w=hb.w*wb.w;

        H2  += dot4(ha,ha)   + dot4(hb,hb);
        T2  += dot4(ta,ta)   + dot4(tb,tb);
        R2  += dot4(ra,ra)   + dot4(rb,rb);
        TR  += dot4(ta,ra)   + dot4(tb,rb);
        HW2 += dot4(hwa,hwa) + dot4(hwb,hwb);
        HWT += dot4(hwa,ta)  + dot4(hwb,tb);
        HWR += dot4(hwa,ra)  + dot4(hwb,rb);
    }

    // reduce across the 4 lanes of each element (2 steps, batched)
#pragma unroll
    for (int m = 1; m <= 2; m <<= 1) {
        H2  += __shfl_xor(H2,  m);
        T2  += __shfl_xor(T2,  m);
        R2  += __shfl_xor(R2,  m);
        TR  += __shfl_xor(TR,  m);
        HW2 += __shfl_xor(HW2, m);
        HWT += __shfl_xor(HWT, m);
        HWR += __shfl_xor(HWR, m);
    }

    // ---- scalar finish (identical math to v2-v5) ----
    float nh = sqrtf(H2 + 1e-15f);
    float sh = (nh > MAXN) ? (MAXN / nh) : 1.0f;
    float h2 = H2 * sh * sh;

    float nt = sqrtf(T2 + 1e-15f);
    float st = (nt > MAXN) ? (MAXN / nt) : 1.0f;
    float t2 = T2 * st * st;

    float nr = sqrtf(R2 + 1e-15f);
    float sr = (nr > MAXN) ? (MAXN / nr) : 1.0f;
    float r2 = R2 * sr * sr;

    float xy = TR * st * sr;

    float nl = sqrtf(h2 + 1e-15f);
    nl = fminf(fmaxf(nl, EPSF), MAXN);
    float lf = 0.5f * logf((1.0f + nl) / (1.0f - nl)) / nl;   // artanh(nl)/nl
    float a0 = lf * sh;
    float v2 = a0 * a0 * HW2;

    float nv = fmaxf(sqrtf(v2 + 1e-15f), EPSF);
    float ef = tanhf(nv) / nv;
    float b0 = ef * a0;
    float hd2 = b0 * b0 * HW2;

    float nhd = sqrtf(hd2 + 1e-15f);
    float shd = (nhd > MAXN) ? (MAXN / nhd) : 1.0f;
    float bb = b0 * shd;
    hd2 = bb * bb * HW2;

    float ct  = 1.0f + 2.0f * xy + r2;
    float cr  = 1.0f - t2;
    float den = fmaxf(1.0f + 2.0f * xy + t2 * r2, EPSF);
    float id  = 1.0f / den;
    float p = id * ct * st;
    float q = id * cr * sr;
    float tl2 = p*p*T2 + 2.0f*p*q*TR + q*q*R2;

    float ntl = sqrtf(tl2 + 1e-15f);
    float stl = (ntl > MAXN) ? (MAXN / ntl) : 1.0f;
    p *= stl; q *= stl;
    tl2 = tl2 * stl * stl;

    float hdtl = bb * (p * HWT + q * HWR);
    float d2   = hd2 + tl2 - 2.0f * hdtl;
    float dn   = fmaxf((1.0f - hd2) * (1.0f - tl2), EPSF);
    float arg  = fmaxf(1.0f + 2.0f * d2 / dn, 1.0f + 1e-7f);
    float dist = acoshf(arg);

    if (sub == 0 && ebase + j < total)
        out[e] = bsum - dist;
}

// f32 fallback (v3 path) if ws too small
__global__ __launch_bounds__(256) void poincare_score_f32_kernel(
    const float* __restrict__ Eh, const float* __restrict__ rvh,
    const float* __restrict__ W, const float* __restrict__ bias0,
    const float* __restrict__ bias1, const int* __restrict__ head_idx,
    const int* __restrict__ rel_idx, const int* __restrict__ tail_idx,
    float* __restrict__ out, int total)
{
    const int tid   = threadIdx.x;
    const int lane4 = tid & 3;
    const int e     = blockIdx.x * 64 + (tid >> 2);
    if (e >= total) return;

    const int hi = head_idx[e];
    const int ri = rel_idx[e];
    const int ti = tail_idx[e];

    const float4* __restrict__ Eh4  = reinterpret_cast<const float4*>(Eh);
    const float4* __restrict__ rvh4 = reinterpret_cast<const float4*>(rvh);
    const float4* __restrict__ W4   = reinterpret_cast<const float4*>(W);

    const float4* __restrict__ hrow = Eh4  + (size_t)hi * 32 + lane4;
    const float4* __restrict__ trow = Eh4  + (size_t)ti * 32 + lane4;
    const float4* __restrict__ rrow = rvh4 + (size_t)ri * 32 + lane4;
    const float4* __restrict__ wrow = W4   + (size_t)ri * 32 + lane4;

    float H2 = 0.f, T2 = 0.f, R2 = 0.f, TR = 0.f;
    float HW2 = 0.f, HWT = 0.f, HWR = 0.f;
#pragma unroll
    for (int jj = 0; jj < 8; ++jj) {
        float4 h = hrow[jj * 4];
        float4 t = trow[jj * 4];
        float4 r = rrow[jj * 4];
        float4 w = wrow[jj * 4];
        float4 hw;
        hw.x = h.x * w.x; hw.y = h.y * w.y; hw.z = h.z * w.z; hw.w = h.w * w.w;
        H2  += dot4(h, h);
        T2  += dot4(t, t);
        R2  += dot4(r, r);
        TR  += dot4(t, r);
        HW2 += dot4(hw, hw);
        HWT += dot4(hw, t);
        HWR += dot4(hw, r);
    }
#pragma unroll
    for (int m = 1; m <= 2; m <<= 1) {
        H2  += __shfl_xor(H2,  m);
        T2  += __shfl_xor(T2,  m);
        R2  += __shfl_xor(R2,  m);
        TR  += __shfl_xor(TR,  m);
        HW2 += __shfl_xor(HW2, m);
        HWT += __shfl_xor(HWT, m);
        HWR += __shfl_xor(HWR, m);
    }

    float nh = sqrtf(H2 + 1e-15f);
    float sh = (nh > MAXN) ? (MAXN / nh) : 1.0f;
    float h2 = H2 * sh * sh;
    float nt = sqrtf(T2 + 1e-15f);
    float st = (nt > MAXN) ? (MAXN / nt) : 1.0f;
    float t2 = T2 * st * st;
    float nr = sqrtf(R2 + 1e-15f);
    float sr = (nr > MAXN) ? (MAXN / nr) : 1.0f;
    float r2 = R2 * sr * sr;
    float xy = TR * st * sr;

    float nl = sqrtf(h2 + 1e-15f);
    nl = fminf(fmaxf(nl, EPSF), MAXN);
    float lf = 0.5f * logf((1.0f + nl) / (1.0f - nl)) / nl;
    float a0 = lf * sh;
    float v2 = a0 * a0 * HW2;
    float nv = fmaxf(sqrtf(v2 + 1e-15f), EPSF);
    float ef = tanhf(nv) / nv;
    float b0 = ef * a0;
    float hd2 = b0 * b0 * HW2;
    float nhd = sqrtf(hd2 + 1e-15f);
    float shd = (nhd > MAXN) ? (MAXN / nhd) : 1.0f;
    float b = b0 * shd;
    hd2 = b * b * HW2;

    float ct  = 1.0f + 2.0f * xy + r2;
    float cr  = 1.0f - t2;
    float den = fmaxf(1.0f + 2.0f * xy + t2 * r2, EPSF);
    float id  = 1.0f / den;
    float p = id * ct * st;
    float q = id * cr * sr;
    float tl2 = p * p * T2 + 2.0f * p * q * TR + q * q * R2;
    float ntl = sqrtf(tl2 + 1e-15f);
    float stl = (ntl > MAXN) ? (MAXN / ntl) : 1.0f;
    p *= stl; q *= stl;
    tl2 = tl2 * stl * stl;

    float hdtl = b * (p * HWT + q * HWR);
    float d2   = hd2 + tl2 - 2.0f * hdtl;
    float dn   = fmaxf((1.0f - hd2) * (1.0f - tl2), EPSF);
    float arg  = fmaxf(1.0f + 2.0f * d2 / dn, 1.0f + 1e-7f);
    float dist = acoshf(arg);

    if (lane4 == 0) {
        out[e] = bias0[hi] + bias1[ti] - dist;
    }
}

extern "C" void kernel_launch(void* const* d_in, const int* in_sizes, int n_in,
                              void* d_out, int out_size, void* d_ws, size_t ws_size,
                              hipStream_t stream) {
    const float* Eh       = (const float*)d_in[0];
    const float* rvh      = (const float*)d_in[1];
    const float* W        = (const float*)d_in[2];
    const float* bias0    = (const float*)d_in[3];
    const float* bias1    = (const float*)d_in[4];
    const int*   head_idx = (const int*)d_in[5];
    const int*   rel_idx  = (const int*)d_in[6];
    const int*   tail_idx = (const int*)d_in[7];
    float* out = (float*)d_out;

    const int total = in_sizes[5];             // B*K = 262144
    const int n_eh  = in_sizes[0];             // N_ENT * DIM
    const int n_rv  = in_sizes[1];             // N_REL * DIM
    const int nRel  = n_rv / 128;
    const int ngE   = n_eh / 8;

    const size_t needE  = (size_t)ngE * 16;           // bf16 Eh bytes
    const size_t needRW = (size_t)nRel * 32 * 16;     // packed r|w bytes
    const size_t need   = needE + needRW;

    if (ws_size >= need && (n_eh & 7) == 0 && (n_rv % 128) == 0) {
        uint4* dstE  = (uint4*)d_ws;
        uint4* dstRW = dstE + ngE;
        const int cwork   = ngE + nRel * 32;
        const int cblocks = (cwork + 255) / 256;
        cvt_kernel<<<cblocks, 256, 0, stream>>>(
            (const uint4*)Eh, (const uint4*)rvh, (const uint4*)W,
            dstE, dstRW, ngE, nRel);

        const int blocks = (total + 63) / 64;
        poincare_score_v7_kernel<<<blocks, 256, 0, stream>>>(
            (const char*)dstE, dstRW, bias0, bias1,
            head_idx, rel_idx, tail_idx, out, total);
    } else {
        const int blocks = (total + 63) / 64;
        poincare_score_f32_kernel<<<blocks, 256, 0, stream>>>(
            Eh, rvh, W, bias0, bias1, head_idx, rel_idx, tail_idx, out, total);
    }
}